// Round 7
// baseline (132.927 us; speedup 1.0000x reference)
//
#include <hip/hip_runtime.h>
#include <math.h>

#define NTOK 9216      // 96*96 tokens
#define CIN  32        // inner channels
#define CC   64        // outer channels
#define NCH1 16        // phase1 n-chunks
#define NT1S 36        // n-tile steps per phase1 chunk: 576/16
#define NCH2 12        // phase2 m-chunks
#define MS2  24        // m-steps (32-wide) per phase2 chunk: 9216/12/32
#define LOG2E 1.4426950408889634f
#define C1INIT (-17.312340490667560f)   // -12*log2e
#define C2INIT (-9.3123404906675595f)   // -12*log2e + 8  (+8 = *256 f16-underflow guard)

typedef _Float16 half8 __attribute__((ext_vector_type(8)));
typedef float    f32x4 __attribute__((ext_vector_type(4)));

static __device__ __forceinline__ float fexp2(float x) {
#if __has_builtin(__builtin_amdgcn_exp2f)
    return __builtin_amdgcn_exp2f(x);
#else
    return exp2f(x);
#endif
}

// ---------------- conv1: 3x3 s2 p1, 4 px x 2 oc per thread, partial over ci ----------------
// 1-D grid 768, block 192. Decode: grp = bid%8 (XCD-affine), ocp = (bid/8)%32, bx = bid/256.
__global__ void conv3x3_quad96(const float* __restrict__ in, const float* __restrict__ w,
                               float* __restrict__ outp) {
    const int bid = blockIdx.x;
    const int grp = bid & 7;
    const int ocp = (bid >> 3) & 31;
    const int bx  = bid >> 8;
    const int t = threadIdx.x;
    const int q = t % 12, ohl = t / 12;
    const int oh = bx * 16 + ohl;
    const int ci0 = grp * 8;
    float a00 = 0.f, a01 = 0.f, a02 = 0.f, a03 = 0.f;
    float a10 = 0.f, a11 = 0.f, a12 = 0.f, a13 = 0.f;
    #pragma unroll
    for (int ci = 0; ci < 8; ++ci) {
        const float* ip = in + (ci0 + ci) * 9216;
        const float* wp0 = w + (2 * ocp) * 576 + (ci0 + ci) * 9;
        const float* wp1 = wp0 + 576;
        #pragma unroll
        for (int kh = 0; kh < 3; ++kh) {
            int ih = oh * 2 - 1 + kh;
            if (ih < 0) continue;            // ih <= 95 always
            const float* rp = ip + ih * 96;
            float ls = (q > 0) ? rp[8 * q - 1] : 0.f;
            float4 fa = *(const float4*)(rp + 8 * q);
            float4 fb = *(const float4*)(rp + 8 * q + 4);
            float w00 = wp0[kh * 3], w01 = wp0[kh * 3 + 1], w02 = wp0[kh * 3 + 2];
            float w10 = wp1[kh * 3], w11 = wp1[kh * 3 + 1], w12 = wp1[kh * 3 + 2];
            a00 = fmaf(ls,   w00, fmaf(fa.x, w01, fmaf(fa.y, w02, a00)));
            a01 = fmaf(fa.y, w00, fmaf(fa.z, w01, fmaf(fa.w, w02, a01)));
            a02 = fmaf(fa.w, w00, fmaf(fb.x, w01, fmaf(fb.y, w02, a02)));
            a03 = fmaf(fb.y, w00, fmaf(fb.z, w01, fmaf(fb.w, w02, a03)));
            a10 = fmaf(ls,   w10, fmaf(fa.x, w11, fmaf(fa.y, w12, a10)));
            a11 = fmaf(fa.y, w10, fmaf(fa.z, w11, fmaf(fa.w, w12, a11)));
            a12 = fmaf(fa.w, w10, fmaf(fb.x, w11, fmaf(fb.y, w12, a12)));
            a13 = fmaf(fb.y, w10, fmaf(fb.z, w11, fmaf(fb.w, w12, a13)));
        }
    }
    float* op = outp + grp * (CC * 2304) + (2 * ocp) * 2304 + oh * 48 + 4 * q;
    *(float4*)op          = make_float4(a00, a01, a02, a03);
    *(float4*)(op + 2304) = make_float4(a10, a11, a12, a13);
}

// ---------------- generic small conv 3x3 s2 p1: partial over ci-groups ----------------
template<int HIN, int HOUT, int CIG>
__global__ void conv3x3_part(const float* __restrict__ in, const float* __restrict__ w,
                             float* __restrict__ outp) {
    const int p = blockIdx.x * blockDim.x + threadIdx.x;
    if (p >= HOUT * HOUT) return;
    const int oc = blockIdx.y, grp = blockIdx.z;
    const int oh = p / HOUT, ow = p % HOUT;
    const int ci0 = grp * CIG;
    float acc = 0.f;
    #pragma unroll
    for (int ci = 0; ci < CIG; ++ci) {
        const float* ip = in + (ci0 + ci) * HIN * HIN;
        const float* wp = w + oc * CC * 9 + (ci0 + ci) * 9;
        #pragma unroll
        for (int kh = 0; kh < 3; ++kh) {
            int ih = oh * 2 - 1 + kh;
            bool okh = (unsigned)ih < (unsigned)HIN;
            #pragma unroll
            for (int kw = 0; kw < 3; ++kw) {
                int iw = ow * 2 - 1 + kw;
                float v = (okh && (unsigned)iw < (unsigned)HIN) ? ip[ih * HIN + iw] : 0.f;
                acc = fmaf(v, wp[kh * 3 + kw], acc);
            }
        }
    }
    outp[grp * (CC * HOUT * HOUT) + oc * HOUT * HOUT + p] = acc;
}

// ---------------- merge conv partials + bias + (leaky)relu, float4 ----------------
template<int NG, int HW, int LRELU>
__global__ void conv_merge4(const float* __restrict__ parts, const float* __restrict__ b,
                            float* __restrict__ out) {
    int i4 = blockIdx.x * 256 + threadIdx.x;    // CC*HW/4 total
    int oc = (i4 * 4) / HW;
    float bb = b[oc];
    float4 acc = make_float4(bb, bb, bb, bb);
    #pragma unroll
    for (int g = 0; g < NG; ++g) {
        float4 p = *(const float4*)(parts + g * (CC * HW) + i4 * 4);
        acc.x += p.x; acc.y += p.y; acc.z += p.z; acc.w += p.w;
    }
    if (LRELU) {
        acc.x = acc.x >= 0.f ? acc.x : 0.2f * acc.x;
        acc.y = acc.y >= 0.f ? acc.y : 0.2f * acc.y;
        acc.z = acc.z >= 0.f ? acc.z : 0.2f * acc.z;
        acc.w = acc.w >= 0.f ? acc.w : 0.2f * acc.w;
    }
    *(float4*)(out + i4 * 4) = acc;
}

// ---------------- gate helper: bilinear 12->96 + sigmoid ----------------
static __device__ __forceinline__ float gate_val(const float* __restrict__ y3c, int n) {
    int h = n / 96, wc = n % 96;
    float fh = (h + 0.5f) * 0.125f - 0.5f;
    float fw = (wc + 0.5f) * 0.125f - 0.5f;
    int h0 = (int)floorf(fh); float ah = fh - (float)h0;
    int w0 = (int)floorf(fw); float aw = fw - (float)w0;
    int h0c = min(max(h0, 0), 11), h1c = min(max(h0 + 1, 0), 11);
    int w0c = min(max(w0, 0), 11), w1c = min(max(w0 + 1, 0), 11);
    float v = (1.f - ah) * ((1.f - aw) * y3c[h0c * 12 + w0c] + aw * y3c[h0c * 12 + w1c])
            +         ah * ((1.f - aw) * y3c[h1c * 12 + w0c] + aw * y3c[h1c * 12 + w1c]);
    return 1.f / (1.f + __expf(-v));
}

// ---------------- fused: gate + 3x 1x1 conv + f16 fragment pack ----------------
// grid 144, block 256. Block covers 64 tokens (4 score-tiles, 2 mt x 2 ct g-tiles).
__global__ __launch_bounds__(256) void fused_proj(
    const float* __restrict__ x, const float* __restrict__ y3,
    const float* __restrict__ gw, const float* __restrict__ gb,
    const float* __restrict__ thw, const float* __restrict__ thb,
    const float* __restrict__ phw, const float* __restrict__ phb,
    _Float16* __restrict__ txF, _Float16* __restrict__ pxF, _Float16* __restrict__ gxF) {
    __shared__ float xgl[64][64];          // [c][n_loc]
    __shared__ _Float16 pr[3][32][66];     // [proj][ci][n_loc] (+2 pad: conflict-free transposed reads)
    const int t = threadIdx.x;
    const int n0 = blockIdx.x * 64;
    for (int idx = t; idx < 64 * 64; idx += 256) {
        int c = idx >> 6, nl = idx & 63;
        int n = n0 + nl;
        float sg = gate_val(y3 + c * 144, n);
        xgl[c][nl] = sg * x[c * NTOK + n];
    }
    __syncthreads();
    const int w = t >> 6, l = t & 63;
    {
        float ag[8], at[8], ap[8];
        #pragma unroll
        for (int j = 0; j < 8; ++j) {
            int ci = w * 8 + j;
            ag[j] = gb[ci]; at[j] = thb[ci]; ap[j] = phb[ci];
        }
        #pragma unroll 4
        for (int c = 0; c < 64; ++c) {
            float v = xgl[c][l];
            #pragma unroll
            for (int j = 0; j < 8; ++j) {
                int ci = w * 8 + j;
                ag[j] = fmaf(gw[ci * CC + c],  v, ag[j]);
                at[j] = fmaf(thw[ci * CC + c], v, at[j]);
                ap[j] = fmaf(phw[ci * CC + c], v, ap[j]);
            }
        }
        #pragma unroll
        for (int j = 0; j < 8; ++j) {
            pr[0][w * 8 + j][l] = (_Float16)(at[j] * LOG2E);
            pr[1][w * 8 + j][l] = (_Float16)ap[j];
            pr[2][w * 8 + j][l] = (_Float16)ag[j];
        }
    }
    __syncthreads();
    const int khi = (l >> 4) * 4;
    {   // txF/pxF: wave w packs tile 4*bid + w
        int tile = blockIdx.x * 4 + w;
        int nl = w * 16 + (l & 15);
        half8 vt, vp;
        #pragma unroll
        for (int e = 0; e < 8; ++e) {
            int c = (e >> 2) * 16 + khi + (e & 3);
            vt[e] = pr[0][c][nl];
            vp[e] = pr[1][c][nl];
        }
        *(half8*)(txF + tile * 512 + l * 8) = vt;
        *(half8*)(pxF + tile * 512 + l * 8) = vp;
    }
    {   // gxF: wave w -> (mt = w>>1, ct = w&1)
        int mt = w >> 1, ct = w & 1;
        int c2 = ct * 16 + (l & 15);
        half8 vg;
        #pragma unroll
        for (int e = 0; e < 8; ++e) {
            int ml = mt * 32 + (e >> 2) * 16 + khi + (e & 3);
            vg[e] = pr[2][c2][ml];
        }
        int gtile = (blockIdx.x * 2 + mt) * 2 + ct;
        *(half8*)(gxF + gtile * 512 + l * 8) = vg;
    }
}

// ---------------- phase 1: Dp[m] = sum_n exp2(s'), 4 m-tiles per wave ----------------
__global__ __launch_bounds__(256) void phase1(const _Float16* __restrict__ txF,
                                              const _Float16* __restrict__ pxF,
                                              float* __restrict__ Dp) {
    int w = threadIdx.x >> 6, l = threadIdx.x & 63;
    int mtile0 = (blockIdx.x * 4 + w) * 4;
    half8 pf[4];
    #pragma unroll
    for (int j = 0; j < 4; ++j)
        pf[j] = *(const half8*)(pxF + (mtile0 + j) * 512 + l * 8);
    f32x4 cini = {C1INIT, C1INIT, C1INIT, C1INIT};
    float dsum[4][4] = {};
    int nt0 = blockIdx.y * NT1S;
    for (int i = 0; i < NT1S; ++i) {
        half8 tf = *(const half8*)(txF + (nt0 + i) * 512 + l * 8);
        #pragma unroll
        for (int j = 0; j < 4; ++j) {
            f32x4 s = __builtin_amdgcn_mfma_f32_16x16x32_f16(pf[j], tf, cini, 0, 0, 0);
            #pragma unroll
            for (int r = 0; r < 4; ++r)
                dsum[j][r] += fexp2(s[r]);
        }
    }
    #pragma unroll
    for (int off = 1; off < 16; off <<= 1)
        #pragma unroll
        for (int j = 0; j < 4; ++j)
            #pragma unroll
            for (int r = 0; r < 4; ++r)
                dsum[j][r] += __shfl_xor(dsum[j][r], off);
    if ((l & 15) == 0) {
        #pragma unroll
        for (int j = 0; j < 4; ++j) {
            int m = (mtile0 + j) * 16 + (l >> 4) * 4;
            #pragma unroll
            for (int r = 0; r < 4; ++r)
                Dp[blockIdx.y * NTOK + m + r] = dsum[j][r];
        }
    }
}

// ---------------- merge D partials -> log2D ----------------
__global__ void mergeD(const float* __restrict__ Dp, float* __restrict__ log2D) {
    int m = blockIdx.x * 256 + threadIdx.x;
    float D = 0.f;
    #pragma unroll
    for (int ch = 0; ch < NCH1; ++ch) D += Dp[ch * NTOK + m];
    log2D[m] = __log2f(D);
}

// ---------------- phase 2: y2 = sum_m 2^(s'-log2D)*g, 4 n-tiles per wave ----------------
__global__ __launch_bounds__(256) void phase2(const _Float16* __restrict__ txF,
                                              const _Float16* __restrict__ pxF,
                                              const _Float16* __restrict__ gxF,
                                              const float* __restrict__ log2D,
                                              float* __restrict__ y2p) {
    int w = threadIdx.x >> 6, l = threadIdx.x & 63;
    int ntile0 = (blockIdx.x * 4 + w) * 4;
    half8 tf[4];
    #pragma unroll
    for (int j = 0; j < 4; ++j)
        tf[j] = *(const half8*)(txF + (ntile0 + j) * 512 + l * 8);
    int khi = (l >> 4) * 4;
    f32x4 zero = {0.f, 0.f, 0.f, 0.f};
    f32x4 c2v = {C2INIT, C2INIT, C2INIT, C2INIT};
    f32x4 acc[4][2];
    #pragma unroll
    for (int j = 0; j < 4; ++j) { acc[j][0] = zero; acc[j][1] = zero; }
    int mbase = blockIdx.y * (NTOK / NCH2);
    for (int ms = 0; ms < MS2; ++ms) {
        int m0 = mbase + ms * 32;
        int mt16 = m0 >> 4;
        half8 pf0 = *(const half8*)(pxF + mt16 * 512 + l * 8);
        half8 pf1 = *(const half8*)(pxF + (mt16 + 1) * 512 + l * 8);
        f32x4 l2a = *(const f32x4*)(log2D + m0 + khi);
        f32x4 l2b = *(const f32x4*)(log2D + m0 + 16 + khi);
        f32x4 cini0 = c2v - l2a;    // per-lane C init folds the softmax denominator
        f32x4 cini1 = c2v - l2b;
        int gt = (m0 >> 5) * 2;
        half8 gf0 = *(const half8*)(gxF + gt * 512 + l * 8);
        half8 gf1 = *(const half8*)(gxF + (gt + 1) * 512 + l * 8);
        #pragma unroll
        for (int j = 0; j < 4; ++j) {
            f32x4 s0 = __builtin_amdgcn_mfma_f32_16x16x32_f16(pf0, tf[j], cini0, 0, 0, 0);
            f32x4 s1 = __builtin_amdgcn_mfma_f32_16x16x32_f16(pf1, tf[j], cini1, 0, 0, 0);
            half8 ff;
            #pragma unroll
            for (int r = 0; r < 4; ++r) {
                ff[r]     = (_Float16)fexp2(s0[r]);
                ff[4 + r] = (_Float16)fexp2(s1[r]);
            }
            acc[j][0] = __builtin_amdgcn_mfma_f32_16x16x32_f16(ff, gf0, acc[j][0], 0, 0, 0);
            acc[j][1] = __builtin_amdgcn_mfma_f32_16x16x32_f16(ff, gf1, acc[j][1], 0, 0, 0);
        }
    }
    float* base = y2p + blockIdx.y * (CIN * NTOK);
    #pragma unroll
    for (int j = 0; j < 4; ++j) {
        int n = (ntile0 + j) * 16 + khi;
        #pragma unroll
        for (int r = 0; r < 4; ++r) {
            base[(l & 15) * NTOK + n + r]        = acc[j][0][r] * 0.00390625f;
            base[(16 + (l & 15)) * NTOK + n + r] = acc[j][1][r] * 0.00390625f;
        }
    }
}

// ---------------- merge y2 partials (float4) ----------------
__global__ void mergeY2(const float* __restrict__ y2p, float* __restrict__ att) {
    int i4 = blockIdx.x * 256 + threadIdx.x;   // 32*9216/4
    float4 s = make_float4(0.f, 0.f, 0.f, 0.f);
    #pragma unroll
    for (int ch = 0; ch < NCH2; ++ch) {
        float4 p = *(const float4*)(y2p + ch * (CIN * NTOK) + i4 * 4);
        s.x += p.x; s.y += p.y; s.z += p.z; s.w += p.w;
    }
    *(float4*)(att + i4 * 4) = s;
}

// ---------------- final 1x1 conv + gated residual (gate recomputed inline) ----------------
__global__ void final_conv(const float* __restrict__ att, const float* __restrict__ Ww,
                           const float* __restrict__ Wb, const float* __restrict__ x,
                           const float* __restrict__ y3, float* __restrict__ out) {
    int co = blockIdx.y;
    int n = blockIdx.x * 256 + threadIdx.x;
    float acc = Wb[co];
    #pragma unroll
    for (int ci = 0; ci < CIN; ++ci)
        acc = fmaf(Ww[co * CIN + ci], att[ci * NTOK + n], acc);
    float sg = gate_val(y3 + co * 144, n);
    out[co * NTOK + n] = acc + sg * x[co * NTOK + n];
}

extern "C" void kernel_launch(void* const* d_in, const int* in_sizes, int n_in,
                              void* d_out, int out_size, void* d_ws, size_t ws_size,
                              hipStream_t stream) {
    const float* x   = (const float*)d_in[0];
    const float* d1w = (const float*)d_in[1];  const float* d1b = (const float*)d_in[2];
    const float* d2w = (const float*)d_in[3];  const float* d2b = (const float*)d_in[4];
    const float* d3w = (const float*)d_in[5];  const float* d3b = (const float*)d_in[6];
    const float* gw  = (const float*)d_in[7];  const float* gb  = (const float*)d_in[8];
    const float* thw = (const float*)d_in[9];  const float* thb = (const float*)d_in[10];
    const float* phw = (const float*)d_in[11]; const float* phb = (const float*)d_in[12];
    const float* Ww  = (const float*)d_in[13]; const float* Wb  = (const float*)d_in[14];
    float* out = (float*)d_out;

    float* W     = (float*)d_ws;
    float* y1    = W;                 // 147456 -> 147456
    float* y2c   = W + 147456;        // 36864  -> 184320
    float* y3    = W + 184320;        // 9216   -> 193536
    float* Dp    = W + 193536;        // 16*9216 = 147456 -> 340992
    float* log2D = W + 340992;        // 9216   -> 350208
    float* att   = W + 350208;        // 294912 -> 645120
    float* y2p   = W + 645120;        // 12*294912 = 3538944 -> 4184064
    _Float16* txF = (_Float16*)(W + 4184064);   // 294912 f16 -> +147456 fl
    _Float16* pxF = (_Float16*)(W + 4331520);
    _Float16* gxF = (_Float16*)(W + 4478976);   // end 4626432 floats = 18.5 MB

    // conv partial buffers: reuse y2p region (dead until phase2)
    float* cp1 = y2p;                 // 8*147456 = 1179648
    float* cp2 = y2p + 1179648;       // 16*36864 = 589824
    float* cp3 = y2p + 1769472;       // 16*9216  = 147456

    // gating branch (reads ORIGINAL x)
    conv3x3_quad96<<<768, 192, 0, stream>>>(x, d1w, cp1);
    conv_merge4<8, 2304, 1><<<144, 256, 0, stream>>>(cp1, d1b, y1);
    conv3x3_part<48, 24, 4><<<dim3(3, CC, 16), 192, 0, stream>>>(y1, d2w, cp2);
    conv_merge4<16, 576, 1><<<36, 256, 0, stream>>>(cp2, d2b, y2c);
    conv3x3_part<24, 12, 4><<<dim3(1, CC, 16), 192, 0, stream>>>(y2c, d3w, cp3);
    conv_merge4<16, 144, 0><<<9, 256, 0, stream>>>(cp3, d3b, y3);

    // fused gate + 1x1 projections + f16 fragment pack
    fused_proj<<<144, 256, 0, stream>>>(x, y3, gw, gb, thw, thb, phw, phb,
                                        txF, pxF, gxF);

    // attention via MFMA
    phase1<<<dim3(36, NCH1), 256, 0, stream>>>(txF, pxF, Dp);
    mergeD<<<36, 256, 0, stream>>>(Dp, log2D);
    phase2<<<dim3(36, NCH2), 256, 0, stream>>>(txF, pxF, gxF, log2D, y2p);
    mergeY2<<<288, 256, 0, stream>>>(y2p, att);

    // output (gate recomputed inline for the residual)
    final_conv<<<dim3(36, CC), 256, 0, stream>>>(att, Ww, Wb, x, y3, out);
}

// Round 8
// 120.717 us; speedup vs baseline: 1.1011x; 1.1011x over previous
//
#include <hip/hip_runtime.h>
#include <math.h>

#define NTOK 9216      // 96*96 tokens
#define CIN  32        // inner channels
#define CC   64        // outer channels
#define NCH1 16        // phase1 n-chunks
#define NT1S 36        // n-tile steps per phase1 chunk: 576/16
#define NCH2 12        // phase2 m-chunks
#define MS2  24        // m-steps (32-wide) per phase2 chunk: 9216/12/32
#define MCH2 768       // m per phase2 chunk
#define LOG2E 1.4426950408889634f
#define C1INIT (-17.312340490667560f)   // -12*log2e
#define C2INIT (-9.3123404906675595f)   // -12*log2e + 8  (+8 = *256 f16-underflow guard)

typedef _Float16 half8 __attribute__((ext_vector_type(8)));
typedef float    f32x4 __attribute__((ext_vector_type(4)));

static __device__ __forceinline__ float fexp2(float x) {
#if __has_builtin(__builtin_amdgcn_exp2f)
    return __builtin_amdgcn_exp2f(x);
#else
    return exp2f(x);
#endif
}

// ---------------- conv1: 3x3 s2 p1, 4 output px/thread, partial over ci ----------------
// grid (3, 64, 8), block 192. thread -> (oh = bx*16 + t/12, ow quad 4q..4q+3), q = t%12.
__global__ void conv3x3_quad96(const float* __restrict__ in, const float* __restrict__ w,
                               float* __restrict__ outp) {
    const int t = threadIdx.x;
    const int q = t % 12, ohl = t / 12;
    const int oh = blockIdx.x * 16 + ohl;
    const int oc = blockIdx.y, grp = blockIdx.z;
    const int ci0 = grp * 8;
    float a0 = 0.f, a1 = 0.f, a2 = 0.f, a3 = 0.f;
    const int iwl = 8 * q - 1;
    #pragma unroll
    for (int ci = 0; ci < 8; ++ci) {
        const float* ip = in + (ci0 + ci) * 9216;
        const float* wp = w + oc * CC * 9 + (ci0 + ci) * 9;
        #pragma unroll
        for (int kh = 0; kh < 3; ++kh) {
            int ih = oh * 2 - 1 + kh;
            if (ih < 0) continue;            // ih <= 95 always
            const float* rp = ip + ih * 96;
            float ls = (q > 0) ? rp[iwl] : 0.f;
            float4 fa = *(const float4*)(rp + 8 * q);
            float4 fb = *(const float4*)(rp + 8 * q + 4);
            float w0 = wp[kh * 3], w1 = wp[kh * 3 + 1], w2 = wp[kh * 3 + 2];
            a0 = fmaf(ls,   w0, fmaf(fa.x, w1, fmaf(fa.y, w2, a0)));
            a1 = fmaf(fa.y, w0, fmaf(fa.z, w1, fmaf(fa.w, w2, a1)));
            a2 = fmaf(fa.w, w0, fmaf(fb.x, w1, fmaf(fb.y, w2, a2)));
            a3 = fmaf(fb.y, w0, fmaf(fb.z, w1, fmaf(fb.w, w2, a3)));
        }
    }
    float4 r = make_float4(a0, a1, a2, a3);
    *(float4*)(outp + grp * (CC * 2304) + oc * 2304 + oh * 48 + 4 * q) = r;
}

// ---------------- generic small conv 3x3 s2 p1: partial over ci-groups ----------------
template<int HIN, int HOUT, int CIG>
__global__ void conv3x3_part(const float* __restrict__ in, const float* __restrict__ w,
                             float* __restrict__ outp) {
    const int p = blockIdx.x * blockDim.x + threadIdx.x;
    if (p >= HOUT * HOUT) return;
    const int oc = blockIdx.y, grp = blockIdx.z;
    const int oh = p / HOUT, ow = p % HOUT;
    const int ci0 = grp * CIG;
    float acc = 0.f;
    #pragma unroll
    for (int ci = 0; ci < CIG; ++ci) {
        const float* ip = in + (ci0 + ci) * HIN * HIN;
        const float* wp = w + oc * CC * 9 + (ci0 + ci) * 9;
        #pragma unroll
        for (int kh = 0; kh < 3; ++kh) {
            int ih = oh * 2 - 1 + kh;
            bool okh = (unsigned)ih < (unsigned)HIN;
            #pragma unroll
            for (int kw = 0; kw < 3; ++kw) {
                int iw = ow * 2 - 1 + kw;
                float v = (okh && (unsigned)iw < (unsigned)HIN) ? ip[ih * HIN + iw] : 0.f;
                acc = fmaf(v, wp[kh * 3 + kw], acc);
            }
        }
    }
    outp[grp * (CC * HOUT * HOUT) + oc * HOUT * HOUT + p] = acc;
}

// ---------------- merge conv partials + bias + (leaky)relu, float4 ----------------
template<int NG, int HW, int LRELU>
__global__ void conv_merge4(const float* __restrict__ parts, const float* __restrict__ b,
                            float* __restrict__ out) {
    int i4 = blockIdx.x * 256 + threadIdx.x;    // CC*HW/4 total
    int oc = (i4 * 4) / HW;
    float bb = b[oc];
    float4 acc = make_float4(bb, bb, bb, bb);
    #pragma unroll
    for (int g = 0; g < NG; ++g) {
        float4 p = *(const float4*)(parts + g * (CC * HW) + i4 * 4);
        acc.x += p.x; acc.y += p.y; acc.z += p.z; acc.w += p.w;
    }
    if (LRELU) {
        acc.x = acc.x >= 0.f ? acc.x : 0.2f * acc.x;
        acc.y = acc.y >= 0.f ? acc.y : 0.2f * acc.y;
        acc.z = acc.z >= 0.f ? acc.z : 0.2f * acc.z;
        acc.w = acc.w >= 0.f ? acc.w : 0.2f * acc.w;
    }
    *(float4*)(out + i4 * 4) = acc;
}

// ---------------- gate helper: bilinear 12->96 + sigmoid ----------------
static __device__ __forceinline__ float gate_val(const float* __restrict__ y3c, int n) {
    int h = n / 96, wc = n % 96;
    float fh = (h + 0.5f) * 0.125f - 0.5f;
    float fw = (wc + 0.5f) * 0.125f - 0.5f;
    int h0 = (int)floorf(fh); float ah = fh - (float)h0;
    int w0 = (int)floorf(fw); float aw = fw - (float)w0;
    int h0c = min(max(h0, 0), 11), h1c = min(max(h0 + 1, 0), 11);
    int w0c = min(max(w0, 0), 11), w1c = min(max(w0 + 1, 0), 11);
    float v = (1.f - ah) * ((1.f - aw) * y3c[h0c * 12 + w0c] + aw * y3c[h0c * 12 + w1c])
            +         ah * ((1.f - aw) * y3c[h1c * 12 + w0c] + aw * y3c[h1c * 12 + w1c]);
    return 1.f / (1.f + __expf(-v));
}

// ---------------- bilinear upsample + sigmoid gate -> xg ----------------
__global__ void gate_kernel(const float* __restrict__ x, const float* __restrict__ y3,
                            float* __restrict__ xg) {
    int idx = blockIdx.x * 256 + threadIdx.x;   // 64*96*96
    int c = idx / 9216, n = idx % 9216;
    float sg = gate_val(y3 + c * 144, n);
    xg[idx] = sg * x[idx];
}

// ---------------- 1x1 convs -> f16 fragments written DIRECTLY ----------------
// grid (36, 32), block 256. Thread owns (ci = blockIdx.y, n).
__global__ void conv1x1_frag(const float* __restrict__ xg,
                             const float* __restrict__ gw, const float* __restrict__ gb,
                             const float* __restrict__ thw, const float* __restrict__ thb,
                             const float* __restrict__ phw, const float* __restrict__ phb,
                             _Float16* __restrict__ txF, _Float16* __restrict__ pxF,
                             _Float16* __restrict__ gxF) {
    int ci = blockIdx.y;
    int n = blockIdx.x * 256 + threadIdx.x;
    float ag = gb[ci], at = thb[ci], ap = phb[ci];
    #pragma unroll 8
    for (int c = 0; c < CC; ++c) {
        float v = xg[c * NTOK + n];
        ag = fmaf(gw[ci * CC + c],  v, ag);
        at = fmaf(thw[ci * CC + c], v, at);
        ap = fmaf(phw[ci * CC + c], v, ap);
    }
    // A-fragment layout (tx/px): tile=n>>4, l=(n&15)|(((ci&15)>>2)<<4), e=((ci>>4)<<2)|(ci&3)
    int addr_ab = (n >> 4) * 512 + (((n & 15) | (((ci & 15) >> 2) << 4)) * 8)
                + (((ci >> 4) << 2) | (ci & 3));
    txF[addr_ab] = (_Float16)(at * LOG2E);
    pxF[addr_ab] = (_Float16)ap;
    // B-fragment layout (g over m=n): gtile=(n>>5)*2+(ci>>4), l=(ci&15)|(((n&15)>>2)<<4),
    // e=(((n>>4)&1)<<2)|(n&3)
    int addr_g = ((n >> 5) * 2 + (ci >> 4)) * 512
               + (((ci & 15) | (((n & 15) >> 2) << 4)) * 8)
               + ((((n >> 4) & 1) << 2) | (n & 3));
    gxF[addr_g] = (_Float16)ag;
}

// ---------------- phase 1: Dp[m] = sum_n exp2(s'), 4 m-tiles per wave ----------------
__global__ __launch_bounds__(256) void phase1(const _Float16* __restrict__ txF,
                                              const _Float16* __restrict__ pxF,
                                              float* __restrict__ Dp) {
    int w = threadIdx.x >> 6, l = threadIdx.x & 63;
    int mtile0 = (blockIdx.x * 4 + w) * 4;
    half8 pf[4];
    #pragma unroll
    for (int j = 0; j < 4; ++j)
        pf[j] = *(const half8*)(pxF + (mtile0 + j) * 512 + l * 8);
    f32x4 cini = {C1INIT, C1INIT, C1INIT, C1INIT};
    float dsum[4][4] = {};
    int nt0 = blockIdx.y * NT1S;
    for (int i = 0; i < NT1S; ++i) {
        half8 tf = *(const half8*)(txF + (nt0 + i) * 512 + l * 8);
        #pragma unroll
        for (int j = 0; j < 4; ++j) {
            f32x4 s = __builtin_amdgcn_mfma_f32_16x16x32_f16(pf[j], tf, cini, 0, 0, 0);
            #pragma unroll
            for (int r = 0; r < 4; ++r)
                dsum[j][r] += fexp2(s[r]);
        }
    }
    #pragma unroll
    for (int off = 1; off < 16; off <<= 1)
        #pragma unroll
        for (int j = 0; j < 4; ++j)
            #pragma unroll
            for (int r = 0; r < 4; ++r)
                dsum[j][r] += __shfl_xor(dsum[j][r], off);
    if ((l & 15) == 0) {
        #pragma unroll
        for (int j = 0; j < 4; ++j) {
            int m = (mtile0 + j) * 16 + (l >> 4) * 4;
            #pragma unroll
            for (int r = 0; r < 4; ++r)
                Dp[blockIdx.y * NTOK + m + r] = dsum[j][r];
        }
    }
}

// ---------------- phase 2: y2 = sum_m 2^(s'-log2D)*g; Dp merged in prologue ----------------
__global__ __launch_bounds__(256) void phase2(const _Float16* __restrict__ txF,
                                              const _Float16* __restrict__ pxF,
                                              const _Float16* __restrict__ gxF,
                                              const float* __restrict__ Dp,
                                              float* __restrict__ y2p) {
    __shared__ float l2D[MCH2];
    int mbase = blockIdx.y * MCH2;
    for (int i = threadIdx.x; i < MCH2; i += 256) {
        float D = 0.f;
        #pragma unroll
        for (int ch = 0; ch < NCH1; ++ch) D += Dp[ch * NTOK + mbase + i];
        l2D[i] = __log2f(D);
    }
    __syncthreads();
    int w = threadIdx.x >> 6, l = threadIdx.x & 63;
    int ntile0 = (blockIdx.x * 4 + w) * 4;
    half8 tf[4];
    #pragma unroll
    for (int j = 0; j < 4; ++j)
        tf[j] = *(const half8*)(txF + (ntile0 + j) * 512 + l * 8);
    int khi = (l >> 4) * 4;
    f32x4 zero = {0.f, 0.f, 0.f, 0.f};
    f32x4 c2v = {C2INIT, C2INIT, C2INIT, C2INIT};
    f32x4 acc[4][2];
    #pragma unroll
    for (int j = 0; j < 4; ++j) { acc[j][0] = zero; acc[j][1] = zero; }
    for (int ms = 0; ms < MS2; ++ms) {
        int m0 = mbase + ms * 32;
        int mloc = ms * 32;
        int mt16 = m0 >> 4;
        half8 pf0 = *(const half8*)(pxF + mt16 * 512 + l * 8);
        half8 pf1 = *(const half8*)(pxF + (mt16 + 1) * 512 + l * 8);
        f32x4 l2a = *(const f32x4*)&l2D[mloc + khi];
        f32x4 l2b = *(const f32x4*)&l2D[mloc + 16 + khi];
        f32x4 cini0 = c2v - l2a;
        f32x4 cini1 = c2v - l2b;
        int gt = (m0 >> 5) * 2;
        half8 gf0 = *(const half8*)(gxF + gt * 512 + l * 8);
        half8 gf1 = *(const half8*)(gxF + (gt + 1) * 512 + l * 8);
        #pragma unroll
        for (int j = 0; j < 4; ++j) {
            f32x4 s0 = __builtin_amdgcn_mfma_f32_16x16x32_f16(pf0, tf[j], cini0, 0, 0, 0);
            f32x4 s1 = __builtin_amdgcn_mfma_f32_16x16x32_f16(pf1, tf[j], cini1, 0, 0, 0);
            half8 ff;
            #pragma unroll
            for (int r = 0; r < 4; ++r) {
                ff[r]     = (_Float16)fexp2(s0[r]);
                ff[4 + r] = (_Float16)fexp2(s1[r]);
            }
            acc[j][0] = __builtin_amdgcn_mfma_f32_16x16x32_f16(ff, gf0, acc[j][0], 0, 0, 0);
            acc[j][1] = __builtin_amdgcn_mfma_f32_16x16x32_f16(ff, gf1, acc[j][1], 0, 0, 0);
        }
    }
    float* base = y2p + blockIdx.y * (CIN * NTOK);
    #pragma unroll
    for (int j = 0; j < 4; ++j) {
        int n = (ntile0 + j) * 16 + khi;
        #pragma unroll
        for (int r = 0; r < 4; ++r) {
            base[(l & 15) * NTOK + n + r]        = acc[j][0][r] * 0.00390625f;
            base[(16 + (l & 15)) * NTOK + n + r] = acc[j][1][r] * 0.00390625f;
        }
    }
}

// ---------------- merge y2 partials (float4) ----------------
__global__ void mergeY2(const float* __restrict__ y2p, float* __restrict__ att) {
    int i4 = blockIdx.x * 256 + threadIdx.x;   // 32*9216/4
    float4 s = make_float4(0.f, 0.f, 0.f, 0.f);
    #pragma unroll
    for (int ch = 0; ch < NCH2; ++ch) {
        float4 p = *(const float4*)(y2p + ch * (CIN * NTOK) + i4 * 4);
        s.x += p.x; s.y += p.y; s.z += p.z; s.w += p.w;
    }
    *(float4*)(att + i4 * 4) = s;
}

// ---------------- final 1x1 conv + residual ----------------
__global__ void final_conv(const float* __restrict__ att, const float* __restrict__ Ww,
                           const float* __restrict__ Wb, const float* __restrict__ xg,
                           float* __restrict__ out) {
    int co = blockIdx.y;
    int n = blockIdx.x * 256 + threadIdx.x;
    float acc = Wb[co];
    #pragma unroll
    for (int ci = 0; ci < CIN; ++ci)
        acc = fmaf(Ww[co * CIN + ci], att[ci * NTOK + n], acc);
    out[co * NTOK + n] = acc + xg[co * NTOK + n];
}

extern "C" void kernel_launch(void* const* d_in, const int* in_sizes, int n_in,
                              void* d_out, int out_size, void* d_ws, size_t ws_size,
                              hipStream_t stream) {
    const float* x   = (const float*)d_in[0];
    const float* d1w = (const float*)d_in[1];  const float* d1b = (const float*)d_in[2];
    const float* d2w = (const float*)d_in[3];  const float* d2b = (const float*)d_in[4];
    const float* d3w = (const float*)d_in[5];  const float* d3b = (const float*)d_in[6];
    const float* gw  = (const float*)d_in[7];  const float* gb  = (const float*)d_in[8];
    const float* thw = (const float*)d_in[9];  const float* thb = (const float*)d_in[10];
    const float* phw = (const float*)d_in[11]; const float* phb = (const float*)d_in[12];
    const float* Ww  = (const float*)d_in[13]; const float* Wb  = (const float*)d_in[14];
    float* out = (float*)d_out;

    float* W    = (float*)d_ws;
    float* xg   = W;                  // 589824 -> 589824
    float* y1   = W + 589824;         // 147456 -> 737280
    float* y2c  = W + 737280;         // 36864  -> 774144
    float* y3   = W + 774144;         // 9216   -> 783360
    float* Dp   = W + 783360;         // 16*9216 = 147456 -> 930816
    float* att  = W + 930816;         // 294912 -> 1225728
    float* y2p  = W + 1225728;        // 12*294912 = 3538944 -> 4764672
    _Float16* txF = (_Float16*)(W + 4764672);   // 294912 f16 = 147456 fl
    _Float16* pxF = (_Float16*)(W + 4912128);
    _Float16* gxF = (_Float16*)(W + 5059584);   // end 5207040 floats = 20.8 MB

    // conv partial buffers: reuse y2p region (dead until phase2)
    float* cp1 = y2p;                 // 8*147456 = 1179648
    float* cp2 = y2p + 1179648;       // 16*36864 = 589824
    float* cp3 = y2p + 1769472;       // 16*9216  = 147456

    // gating branch (reads ORIGINAL x)
    conv3x3_quad96<<<dim3(3, CC, 8), 192, 0, stream>>>(x, d1w, cp1);
    conv_merge4<8, 2304, 1><<<144, 256, 0, stream>>>(cp1, d1b, y1);
    conv3x3_part<48, 24, 4><<<dim3(3, CC, 16), 192, 0, stream>>>(y1, d2w, cp2);
    conv_merge4<16, 576, 1><<<36, 256, 0, stream>>>(cp2, d2b, y2c);
    conv3x3_part<24, 12, 4><<<dim3(1, CC, 16), 192, 0, stream>>>(y2c, d3w, cp3);
    conv_merge4<16, 144, 0><<<9, 256, 0, stream>>>(cp3, d3b, y3);
    gate_kernel<<<2304, 256, 0, stream>>>(x, y3, xg);

    // 1x1 projections -> f16 fragments direct
    conv1x1_frag<<<dim3(36, CIN), 256, 0, stream>>>(xg, gw, gb, thw, thb, phw, phb,
                                                    txF, pxF, gxF);

    // attention via MFMA
    phase1<<<dim3(36, NCH1), 256, 0, stream>>>(txF, pxF, Dp);
    phase2<<<dim3(36, NCH2), 256, 0, stream>>>(txF, pxF, gxF, Dp, y2p);
    mergeY2<<<288, 256, 0, stream>>>(y2p, att);

    // output
    final_conv<<<dim3(36, CC), 256, 0, stream>>>(att, Ww, Wb, xg, out);
}